// Round 6
// baseline (532.141 us; speedup 1.0000x reference)
//
#include <hip/hip_runtime.h>
#include <hip/hip_bf16.h>

typedef __attribute__((ext_vector_type(8))) short short8;
typedef __attribute__((ext_vector_type(4))) float f32x4;
typedef __attribute__((ext_vector_type(16))) float f32x16;
typedef __attribute__((ext_vector_type(4))) unsigned short ushort4v;
typedef __attribute__((ext_vector_type(4))) float float4v;
typedef __attribute__((ext_vector_type(2))) unsigned int uint32x2;
typedef __attribute__((ext_vector_type(4))) unsigned int uint32x4;

#define NB 2
#define NS 4096
#define ND 1024
#define NH 16
#define NHD 64

// 0.125 * log2(e): folds the 1/sqrt(64) score scale AND the exp->exp2
// conversion into the Q projection (exact up to one fp32 rounding).
#define QSCALE 0.18033688011112042f

__device__ __forceinline__ unsigned short f2bf(float x) {
    union { float f; unsigned u; } v; v.f = x;
    unsigned r = v.u + 0x7FFFu + ((v.u >> 16) & 1u);
    return (unsigned short)(r >> 16);
}

// pack 2 f32 -> u32 of 2 bf16 (RNE), dst[15:0]=lo
__device__ __forceinline__ unsigned cvt_pk_bf16(float lo, float hi) {
    unsigned r;
    asm("v_cvt_pk_bf16_f32 %0, %1, %2" : "=v"(r) : "v"(lo), "v"(hi));
    return r;
}

// async global->LDS, 16B per lane. LDS dest = wave-uniform base + lane*16.
__device__ __forceinline__ void gload_lds16(const unsigned short* g, unsigned short* l) {
    __builtin_amdgcn_global_load_lds(
        (const __attribute__((address_space(1))) void*)g,
        (__attribute__((address_space(3))) void*)l,
        16, 0, 0);
}

__global__ void rope_table_kernel(float* __restrict__ cosT, float* __restrict__ sinT) {
    int i = blockIdx.x * blockDim.x + threadIdx.x;  // [0, NS*32)
    int p = i & 31, s = i >> 5;
    float theta = exp2f(-(float)(2 * p) * (13.287712379549449f / 64.0f));  // 10000^(-2p/64)
    float ang = (float)s * theta;
    float sv, cv;
    sincosf(ang, &sv, &cv);
    cosT[i] = cv; sinT[i] = sv;
}

// fp32 -> bf16 elementwise cast, 8 elems/thread (32B read, 16B write).
__global__ void cast_bf16_kernel(const float* __restrict__ in, unsigned short* __restrict__ out, int n8) {
    int i = blockIdx.x * blockDim.x + threadIdx.x;
    if (i >= n8) return;
    float4v a0 = *(const float4v*)(&in[(size_t)i * 8]);
    float4v a1 = *(const float4v*)(&in[(size_t)i * 8 + 4]);
    short8 s8;
    s8[0] = (short)f2bf(a0.x); s8[1] = (short)f2bf(a0.y);
    s8[2] = (short)f2bf(a0.z); s8[3] = (short)f2bf(a0.w);
    s8[4] = (short)f2bf(a1.x); s8[5] = (short)f2bf(a1.y);
    s8[6] = (short)f2bf(a1.z); s8[7] = (short)f2bf(a1.w);
    *(short8*)(&out[(size_t)i * 8]) = s8;
}

// C = A @ W^T + bias. A: [8192][1024] bf16. W: [1024][1024] bf16 row-major.
// Round-6: BM=128 x BN=64 tile (grid 16x64 = 1024 blocks = 4/CU; the old
// 128x128 grid was 512 = 2/CU and latency-starved). BK=32, linear LDS
// (required by global_load_lds), width-16 staging, ds_read_b128 fragments.
// Wave layout: 2x2, each wave owns 64m x 32n (acc[4][2]).
// EPI 0: plain -> out float32 row-major [8192][1024]  (d_out is fp32!)
// EPI 1: RoPE  -> out [B,H,S,HD] bf16, scaled by oscale (Q pre-scaling)
// EPI 2: V^T   -> out [B,H,HD,S] bf16
template<int EPI>
__global__ __launch_bounds__(256, 2) void gemm_kernel(
    const unsigned short* __restrict__ A,
    const unsigned short* __restrict__ Wb,
    const float* __restrict__ bias,
    void* __restrict__ outv,
    const float* __restrict__ cosT,
    const float* __restrict__ sinT,
    float oscale)
{
    __shared__ unsigned short As[128 * 32];  // linear: row stride 32 (64B)
    __shared__ unsigned short Bs[64 * 32];
    const int t = threadIdx.x;
    const int wave = t >> 6, lane = t & 63;
    const int quad = lane >> 4, l15 = lane & 15;
    const int wm = (wave & 1) * 64, wn = (wave >> 1) * 32;
    const int m0 = blockIdx.y * 128, n0 = blockIdx.x * 64;

    f32x4 acc[4][2];
#pragma unroll
    for (int i = 0; i < 4; i++)
#pragma unroll
        for (int j = 0; j < 2; j++)
            acc[i][j] = f32x4{0.f, 0.f, 0.f, 0.f};

    for (int k0 = 0; k0 < ND; k0 += 32) {
        // A: 2 loads/thread (128 rows), B: 1 load/thread (64 rows)
#pragma unroll
        for (int p = 0; p < 2; p++) {
            int idx = p * 256 + t;
            int r = idx >> 2, c = (idx & 3) * 8;
            unsigned short* ldsA = &As[(size_t)(p * 256 + wave * 64) * 8];
            gload_lds16(&A[(size_t)(m0 + r) * ND + k0 + c], ldsA);
        }
        {
            int r = t >> 2, c = (t & 3) * 8;
            unsigned short* ldsB = &Bs[(size_t)(wave * 64) * 8];
            gload_lds16(&Wb[(size_t)(n0 + r) * ND + k0 + c], ldsB);
        }
        __syncthreads();  // compiler emits vmcnt(0) drain here

        short8 af[4], bfr[2];
#pragma unroll
        for (int mt = 0; mt < 4; mt++)
            af[mt] = *(const short8*)(&As[(wm + mt * 16 + l15) * 32 + quad * 8]);
#pragma unroll
        for (int nt = 0; nt < 2; nt++)
            bfr[nt] = *(const short8*)(&Bs[(wn + nt * 16 + l15) * 32 + quad * 8]);
#pragma unroll
        for (int mt = 0; mt < 4; mt++)
#pragma unroll
            for (int nt = 0; nt < 2; nt++) {
                if (EPI == 0)
                    acc[mt][nt] = __builtin_amdgcn_mfma_f32_16x16x32_bf16(bfr[nt], af[mt], acc[mt][nt], 0, 0, 0);
                else
                    acc[mt][nt] = __builtin_amdgcn_mfma_f32_16x16x32_bf16(af[mt], bfr[nt], acc[mt][nt], 0, 0, 0);
            }
        __syncthreads();
    }

    if (EPI == 0) {
        // operands swapped: D[m=W-row -> quad*4+r][n=seq -> l15]; fp32 output
        float* out = (float*)outv;
#pragma unroll
        for (int mt = 0; mt < 4; mt++) {
            int gm = m0 + wm + mt * 16 + l15;  // seq row
#pragma unroll
            for (int nt = 0; nt < 2; nt++) {
                int gn0 = n0 + wn + nt * 16 + quad * 4;  // feature
                float4v fv;
#pragma unroll
                for (int r = 0; r < 4; r++)
                    fv[r] = acc[mt][nt][r] + bias[gn0 + r];
                *(float4v*)(&out[(size_t)gm * ND + gn0]) = fv;
            }
        }
    } else if (EPI == 1) {
        // D[m=seq -> quad*4+r][n=feature -> l15]
        unsigned short* out = (unsigned short*)outv;
#pragma unroll
        for (int nt = 0; nt < 2; nt++) {
            int gn = n0 + wn + nt * 16 + l15;
            int h = gn >> 6, hd = gn & 63, pr = hd >> 1, im = gn & 1;
            float bv = bias[gn];
#pragma unroll
            for (int mt = 0; mt < 4; mt++) {
                int gm0 = m0 + wm + mt * 16 + quad * 4;
#pragma unroll
                for (int r = 0; r < 4; r++) {
                    int gm = gm0 + r;
                    int b = gm >> 12, s = gm & 4095;
                    float v = acc[mt][nt][r] + bv;
                    float pv = __shfl_xor(v, 1, 64);  // partner feature gn^1, same seq
                    float cv = cosT[s * 32 + pr], sv = sinT[s * 32 + pr];
                    float o = im ? (pv * sv + v * cv) : (v * cv - pv * sv);
                    out[((size_t)(b * NH + h) * NS + s) * NHD + hd] = f2bf(o * oscale);
                }
            }
        }
    } else {
        // V^T: out[((b*H+h)*HD+hd)*S + s]
        unsigned short* out = (unsigned short*)outv;
#pragma unroll
        for (int nt = 0; nt < 2; nt++) {
            int gn = n0 + wn + nt * 16 + l15;
            int h = gn >> 6, hd = gn & 63;
            float bv = bias[gn];
#pragma unroll
            for (int mt = 0; mt < 4; mt++) {
                int gm0 = m0 + wm + mt * 16 + quad * 4;
                int b = gm0 >> 12, s0 = gm0 & 4095;
                ushort4v pk;
#pragma unroll
                for (int r = 0; r < 4; r++)
                    pk[r] = f2bf(acc[mt][nt][r] + bv);
                *(ushort4v*)(&out[((size_t)(b * NH + h) * NHD + hd) * NS + s0]) = pk;
            }
        }
    }
}

// Flash attention, 32x32-MFMA in-register-P structure (m214-v22 style).
// Qr: [BH][S][64] bf16, RoPE'd AND pre-scaled by 0.125*log2e. Kr: same, unscaled.
// Vt: [BH][64][S] bf16. Yatt: [B*S][1024] bf16.
// Block: 128 q-rows of one (b,h); wave owns 32 q-rows. Per 128-key tile:
//   S^T = K.Q^T via mfma_32x32x16 (A=K rows, B=Q rows). D: col(lane&31)=q,
//   row=(reg&3)+8*(reg>>2)+4*(lane>>5)=key. Each lane: ONE q, 64 of 128 keys;
//   partner lane^32 has the rest -> softmax = in-lane tree + ONE xor32 shfl.
//   P -> bf16 via cvt_pk (key-consecutive quartets), then ONE
//   v_permlane32_swap_b32 per register pair assembles PV B-frags in-register.
//   NO P LDS round-trip. LDS = Ks+Vs only (35840 B). Persistent zero f32x16
//   feeds each kt-chain's first MFMA (no per-iter sa re-zeroing).
__global__ __launch_bounds__(256, 2) void flash_kernel(
    const unsigned short* __restrict__ Qr,
    const unsigned short* __restrict__ Kr,
    const unsigned short* __restrict__ Vt,
    unsigned short* __restrict__ Yatt)
{
    __shared__ unsigned short Ks[128 * 72];    // pad 64->72 (16B-aligned rows)
    __shared__ unsigned short Vs[64 * 136];    // pad 128->136
    const int t = threadIdx.x;
    const int wave = t >> 6, lane = t & 63;
    const int l31 = lane & 31, h = lane >> 5;
    const int bh = blockIdx.y;
    const int qb = blockIdx.x * 128;
    const int wq = wave * 32;
    const size_t base = (size_t)bh * NS * NHD;

    // Q B-frags: row q = qb+wq+l31, k(d) = ks*16 + h*8 + e
    short8 qf[4];
#pragma unroll
    for (int ks = 0; ks < 4; ks++)
        qf[ks] = *(const short8*)(&Qr[base + (size_t)(qb + wq + l31) * NHD + ks * 16 + h * 8]);

    f32x16 zacc;
#pragma unroll
    for (int r = 0; r < 16; r++)
        zacc[r] = 0.f;

    f32x16 accO[2];
    accO[0] = zacc; accO[1] = zacc;
    float mrow = -1e30f, lrow = 0.f;

    for (int j0 = 0; j0 < NS; j0 += 128) {
        // stage K/V tile
#pragma unroll
        for (int p = 0; p < 4; p++) {
            int idx = p * 256 + t;
            { int r = idx >> 3, c = (idx & 7) * 8;
              *(short8*)(&Ks[r * 72 + c]) = *(const short8*)(&Kr[base + (size_t)(j0 + r) * NHD + c]); }
            { int r = idx >> 4, c = (idx & 15) * 8;
              *(short8*)(&Vs[r * 136 + c]) = *(const short8*)(&Vt[(size_t)(bh * NHD + r) * NS + j0 + c]); }
        }
        __syncthreads();

        // S^T = K . Q^T (exp2 domain; Q pre-scaled)
        f32x16 sa[4];
        __builtin_amdgcn_s_setprio(1);
#pragma unroll
        for (int kt = 0; kt < 4; kt++) {
            short8 ak0 = *(const short8*)(&Ks[(kt * 32 + l31) * 72 + h * 8]);
            f32x16 s = __builtin_amdgcn_mfma_f32_32x32x16_bf16(ak0, qf[0], zacc, 0, 0, 0);
#pragma unroll
            for (int ks = 1; ks < 4; ks++) {
                short8 ak = *(const short8*)(&Ks[(kt * 32 + l31) * 72 + ks * 16 + h * 8]);
                s = __builtin_amdgcn_mfma_f32_32x32x16_bf16(ak, qf[ks], s, 0, 0, 0);
            }
            sa[kt] = s;
        }
        __builtin_amdgcn_s_setprio(0);

        // --- softmax: each lane owns one q (l31), 64 of 128 keys ---
        float mx = -1e30f;
#pragma unroll
        for (int kt = 0; kt < 4; kt++) {
            float m0v = fmaxf(fmaxf(sa[kt][0], sa[kt][1]), fmaxf(sa[kt][2], sa[kt][3]));
            float m1v = fmaxf(fmaxf(sa[kt][4], sa[kt][5]), fmaxf(sa[kt][6], sa[kt][7]));
            float m2v = fmaxf(fmaxf(sa[kt][8], sa[kt][9]), fmaxf(sa[kt][10], sa[kt][11]));
            float m3v = fmaxf(fmaxf(sa[kt][12], sa[kt][13]), fmaxf(sa[kt][14], sa[kt][15]));
            mx = fmaxf(mx, fmaxf(fmaxf(m0v, m1v), fmaxf(m2v, m3v)));
        }
        mx = fmaxf(mx, __shfl_xor(mx, 32, 64));
        // T13 defer-max: rescale only when tile max exceeds running max by >8
        if (!__all(mx <= mrow + 8.0f)) {
            float mnew = fmaxf(mrow, mx);
            float alpha = exp2f(mrow - mnew);
            lrow *= alpha;
#pragma unroll
            for (int dt = 0; dt < 2; dt++)
#pragma unroll
                for (int r = 0; r < 16; r++)
                    accO[dt][r] *= alpha;
            mrow = mnew;
        }
        float ls0 = 0.f, ls1 = 0.f, ls2 = 0.f, ls3 = 0.f;
        unsigned pk[4][4][2];  // [key-tile][quartet g][pair j]
#pragma unroll
        for (int kt = 0; kt < 4; kt++)
#pragma unroll
            for (int g = 0; g < 4; g++) {
                float p0 = exp2f(sa[kt][4 * g + 0] - mrow);
                float p1 = exp2f(sa[kt][4 * g + 1] - mrow);
                float p2 = exp2f(sa[kt][4 * g + 2] - mrow);
                float p3 = exp2f(sa[kt][4 * g + 3] - mrow);
                ls0 += p0; ls1 += p1; ls2 += p2; ls3 += p3;
                pk[kt][g][0] = cvt_pk_bf16(p0, p1);
                pk[kt][g][1] = cvt_pk_bf16(p2, p3);
            }
        float lsum = (ls0 + ls1) + (ls2 + ls3);
        lsum += __shfl_xor(lsum, 32, 64);
        lrow += lsum;

        // in-register P redistribution: swap vdst_hi <-> vsrc_lo.
        // After swap(pk[t][2u][j], pk[t][2u+1][j]):
        //   pk[t][2u][j]   = quartetA (keys 32t+16u+8h + 2j+{0,1})
        //   pk[t][2u+1][j] = quartetB (keys 32t+16u+8h+4 + 2j+{0,1})
#pragma unroll
        for (int t2 = 0; t2 < 4; t2++)
#pragma unroll
            for (int u = 0; u < 2; u++)
#pragma unroll
                for (int j = 0; j < 2; j++)
                    asm volatile("v_permlane32_swap_b32 %0, %1"
                                 : "+v"(pk[t2][2 * u][j]), "+v"(pk[t2][2 * u + 1][j]));

        // PV: O^T[d][q] += V^T . P^T, B-frag assembled from swapped pk
        __builtin_amdgcn_s_setprio(1);
#pragma unroll
        for (int ks2 = 0; ks2 < 8; ks2++) {
            const int t2 = ks2 >> 1, u = ks2 & 1;
            uint32x4 bw;
            bw.x = pk[t2][2 * u][0];     bw.y = pk[t2][2 * u][1];
            bw.z = pk[t2][2 * u + 1][0]; bw.w = pk[t2][2 * u + 1][1];
            short8 bp = __builtin_bit_cast(short8, bw);
#pragma unroll
            for (int dt = 0; dt < 2; dt++) {
                short8 av = *(const short8*)(&Vs[(dt * 32 + l31) * 136 + ks2 * 16 + h * 8]);
                accO[dt] = __builtin_amdgcn_mfma_f32_32x32x16_bf16(av, bp, accO[dt], 0, 0, 0);
            }
        }
        __builtin_amdgcn_s_setprio(0);
        __syncthreads();
    }

    // epilogue: lane owns q = l31; accO row = 8g + 4h + (reg&3) within dt*32
    int b = bh >> 4, hh = bh & 15;
    float rl = 1.f / lrow;
    int s = qb + wq + l31;
#pragma unroll
    for (int dt = 0; dt < 2; dt++)
#pragma unroll
        for (int g = 0; g < 4; g++) {
            uint32x2 w;
            w.x = cvt_pk_bf16(accO[dt][4 * g + 0] * rl, accO[dt][4 * g + 1] * rl);
            w.y = cvt_pk_bf16(accO[dt][4 * g + 2] * rl, accO[dt][4 * g + 3] * rl);
            int d0 = dt * 32 + 8 * g + 4 * h;
            *(uint32x2*)(&Yatt[((size_t)(b * NS + s)) * ND + hh * NHD + d0]) = w;
        }
}

extern "C" void kernel_launch(void* const* d_in, const int* in_sizes, int n_in,
                              void* d_out, int out_size, void* d_ws, size_t ws_size,
                              hipStream_t stream) {
    // dict order (contractual): consulta, chave, valor, Wq, bq, Wk, bk, Wv, bv, Wo, bo
    const float* consulta = (const float*)d_in[0];
    const float* chave    = (const float*)d_in[1];
    const float* valor    = (const float*)d_in[2];
    const float* Wq = (const float*)d_in[3];
    const float* bq = (const float*)d_in[4];
    const float* Wk = (const float*)d_in[5];
    const float* bk = (const float*)d_in[6];
    const float* Wv = (const float*)d_in[7];
    const float* bv = (const float*)d_in[8];
    const float* Wo = (const float*)d_in[9];
    const float* bo = (const float*)d_in[10];

    const size_t NX = (size_t)8192 * 1024;

    float* cosT = (float*)d_ws;
    float* sinT = cosT + (size_t)NS * 32;
    unsigned short* Qrb = (unsigned short*)(sinT + (size_t)NS * 32);
    unsigned short* Krb = Qrb + NX;
    unsigned short* Vtb = Krb + NX;
    unsigned short* Yat = Vtb + NX;
    unsigned short* Abf = Yat + NX;            // bf16 activation staging (reused)
    unsigned short* Wbf = Abf + NX;            // bf16 weight staging (reused)

    rope_table_kernel<<<NS * 32 / 256, 256, 0, stream>>>(cosT, sinT);

    const int ACT8 = (int)(NX / 8);   // 1048576 vec8 chunks
    const int W8 = ND * ND / 8;       // 131072

    dim3 ggrid(16, 64);   // BN=64: 1024 blocks = 4/CU

    cast_bf16_kernel<<<ACT8 / 256, 256, 0, stream>>>(consulta, Abf, ACT8);
    cast_bf16_kernel<<<W8 / 256, 256, 0, stream>>>(Wq, Wbf, W8);
    gemm_kernel<1><<<ggrid, 256, 0, stream>>>(Abf, Wbf, bq, Qrb, cosT, sinT, QSCALE);

    cast_bf16_kernel<<<ACT8 / 256, 256, 0, stream>>>(chave, Abf, ACT8);
    cast_bf16_kernel<<<W8 / 256, 256, 0, stream>>>(Wk, Wbf, W8);
    gemm_kernel<1><<<ggrid, 256, 0, stream>>>(Abf, Wbf, bk, Krb, cosT, sinT, 1.0f);

    cast_bf16_kernel<<<ACT8 / 256, 256, 0, stream>>>(valor, Abf, ACT8);
    cast_bf16_kernel<<<W8 / 256, 256, 0, stream>>>(Wv, Wbf, W8);
    gemm_kernel<2><<<ggrid, 256, 0, stream>>>(Abf, Wbf, bv, Vtb, cosT, sinT, 1.0f);

    flash_kernel<<<dim3(32, 32), 256, 0, stream>>>(Qrb, Krb, Vtb, Yat);

    // d_out is FLOAT32 (reference output dtype)
    cast_bf16_kernel<<<W8 / 256, 256, 0, stream>>>(Wo, Wbf, W8);
    gemm_kernel<0><<<ggrid, 256, 0, stream>>>(Yat, Wbf, bo, d_out, cosT, sinT, 1.0f);
}

// Round 8
// 524.428 us; speedup vs baseline: 1.0147x; 1.0147x over previous
//
#include <hip/hip_runtime.h>
#include <hip/hip_bf16.h>

typedef __attribute__((ext_vector_type(8))) short short8;
typedef __attribute__((ext_vector_type(4))) float f32x4;
typedef __attribute__((ext_vector_type(16))) float f32x16;
typedef __attribute__((ext_vector_type(4))) unsigned short ushort4v;
typedef __attribute__((ext_vector_type(4))) float float4v;
typedef __attribute__((ext_vector_type(2))) unsigned int uint32x2;
typedef __attribute__((ext_vector_type(4))) unsigned int uint32x4;

#define NB 2
#define NS 4096
#define ND 1024
#define NH 16
#define NHD 64

// 0.125 * log2(e): folds the 1/sqrt(64) score scale AND the exp->exp2
// conversion into the Q projection (exact up to one fp32 rounding).
#define QSCALE 0.18033688011112042f

__device__ __forceinline__ unsigned short f2bf(float x) {
    union { float f; unsigned u; } v; v.f = x;
    unsigned r = v.u + 0x7FFFu + ((v.u >> 16) & 1u);
    return (unsigned short)(r >> 16);
}

// pack 2 f32 -> u32 of 2 bf16 (RNE), dst[15:0]=lo
__device__ __forceinline__ unsigned cvt_pk_bf16(float lo, float hi) {
    unsigned r;
    asm("v_cvt_pk_bf16_f32 %0, %1, %2" : "=v"(r) : "v"(lo), "v"(hi));
    return r;
}

// async global->LDS, 16B per lane. LDS dest = wave-uniform base + lane*16.
__device__ __forceinline__ void gload_lds16(const unsigned short* g, unsigned short* l) {
    __builtin_amdgcn_global_load_lds(
        (const __attribute__((address_space(1))) void*)g,
        (__attribute__((address_space(3))) void*)l,
        16, 0, 0);
}

__global__ void rope_table_kernel(float* __restrict__ cosT, float* __restrict__ sinT) {
    int i = blockIdx.x * blockDim.x + threadIdx.x;  // [0, NS*32)
    int p = i & 31, s = i >> 5;
    float theta = exp2f(-(float)(2 * p) * (13.287712379549449f / 64.0f));  // 10000^(-2p/64)
    float ang = (float)s * theta;
    float sv, cv;
    sincosf(ang, &sv, &cv);
    cosT[i] = cv; sinT[i] = sv;
}

// fp32 -> bf16 elementwise cast, 8 elems/thread (32B read, 16B write).
__global__ void cast_bf16_kernel(const float* __restrict__ in, unsigned short* __restrict__ out, int n8) {
    int i = blockIdx.x * blockDim.x + threadIdx.x;
    if (i >= n8) return;
    float4v a0 = *(const float4v*)(&in[(size_t)i * 8]);
    float4v a1 = *(const float4v*)(&in[(size_t)i * 8 + 4]);
    short8 s8;
    s8[0] = (short)f2bf(a0.x); s8[1] = (short)f2bf(a0.y);
    s8[2] = (short)f2bf(a0.z); s8[3] = (short)f2bf(a0.w);
    s8[4] = (short)f2bf(a1.x); s8[5] = (short)f2bf(a1.y);
    s8[6] = (short)f2bf(a1.z); s8[7] = (short)f2bf(a1.w);
    *(short8*)(&out[(size_t)i * 8]) = s8;
}

// Fused QKV projection GEMM. W3: stacked [3072][1024] bf16 (Wq;Wk;Wv) in
// merged mode, or a single [1024][1024] weight in fallback mode.
// Block picks which = (n0g>>10)+which_base: 0 -> Q (RoPE, QSCALE), 1 -> K
// (RoPE), 2 -> V^T.  128x128 tile, BK=32, linear LDS + width-16
// global_load_lds (m97 structure).  launch_bounds(256,3): VGPR cap ~170
// (live ~126, no spill) -> 3 blocks/CU resident; merged grid 24x64 = 1536
// blocks beats the grid-limited 2/CU of 512-block dispatches.
__global__ __launch_bounds__(256, 3) void gemm_qkv_kernel(
    const unsigned short* __restrict__ A0,
    const unsigned short* __restrict__ A1,
    const unsigned short* __restrict__ A2,
    const unsigned short* __restrict__ W3,
    const float* __restrict__ biasq,
    const float* __restrict__ biask,
    const float* __restrict__ biasv,
    unsigned short* __restrict__ Qrb,
    unsigned short* __restrict__ Krb,
    unsigned short* __restrict__ Vtb,
    const float* __restrict__ cosT,
    const float* __restrict__ sinT,
    int which_base)
{
    __shared__ unsigned short As[128 * 32];  // linear: row stride 32 (64B)
    __shared__ unsigned short Bs[128 * 32];
    const int t = threadIdx.x;
    const int wave = t >> 6, lane = t & 63;
    const int quad = lane >> 4, l15 = lane & 15;
    const int wm = (wave & 1) * 64, wn = (wave >> 1) * 64;
    const int m0 = blockIdx.y * 128;
    const int n0g = blockIdx.x * 128;              // row into stacked W3
    const int which = (n0g >> 10) + which_base;    // 0=Q 1=K 2=V
    const int n0 = n0g & 1023;                     // feature within head-dim space
    const unsigned short* A = (which == 0) ? A0 : (which == 1) ? A1 : A2;

    f32x4 acc[4][4];
#pragma unroll
    for (int i = 0; i < 4; i++)
#pragma unroll
        for (int j = 0; j < 4; j++)
            acc[i][j] = f32x4{0.f, 0.f, 0.f, 0.f};

    for (int k0 = 0; k0 < ND; k0 += 32) {
#pragma unroll
        for (int p = 0; p < 2; p++) {
            int idx = p * 256 + t;
            int r = idx >> 2, c = (idx & 3) * 8;
            unsigned short* ldsA = &As[(size_t)(p * 256 + wave * 64) * 8];
            unsigned short* ldsB = &Bs[(size_t)(p * 256 + wave * 64) * 8];
            gload_lds16(&A[(size_t)(m0 + r) * ND + k0 + c], ldsA);
            gload_lds16(&W3[(size_t)(n0g + r) * ND + k0 + c], ldsB);
        }
        __syncthreads();  // compiler emits vmcnt(0) drain here

        short8 af[4], bfr[4];
#pragma unroll
        for (int mt = 0; mt < 4; mt++)
            af[mt] = *(const short8*)(&As[(wm + mt * 16 + l15) * 32 + quad * 8]);
#pragma unroll
        for (int nt = 0; nt < 4; nt++)
            bfr[nt] = *(const short8*)(&Bs[(wn + nt * 16 + l15) * 32 + quad * 8]);
#pragma unroll
        for (int mt = 0; mt < 4; mt++)
#pragma unroll
            for (int nt = 0; nt < 4; nt++)
                acc[mt][nt] = __builtin_amdgcn_mfma_f32_16x16x32_bf16(af[mt], bfr[nt], acc[mt][nt], 0, 0, 0);
        __syncthreads();
    }

    if (which < 2) {
        // RoPE epilogue. D[m=seq -> quad*4+r][n=feature -> l15]
        unsigned short* out = (which == 0) ? Qrb : Krb;
        const float* bias = (which == 0) ? biasq : biask;
        const float oscale = (which == 0) ? QSCALE : 1.0f;
#pragma unroll
        for (int nt = 0; nt < 4; nt++) {
            int gn = n0 + wn + nt * 16 + l15;
            int h = gn >> 6, hd = gn & 63, pr = hd >> 1, im = gn & 1;
            float bvv = bias[gn];
#pragma unroll
            for (int mt = 0; mt < 4; mt++) {
                int gm0 = m0 + wm + mt * 16 + quad * 4;
#pragma unroll
                for (int r = 0; r < 4; r++) {
                    int gm = gm0 + r;
                    int b = gm >> 12, s = gm & 4095;
                    float v = acc[mt][nt][r] + bvv;
                    float pv = __shfl_xor(v, 1, 64);  // partner feature gn^1, same seq
                    float cv = cosT[s * 32 + pr], sv = sinT[s * 32 + pr];
                    float o = im ? (pv * sv + v * cv) : (v * cv - pv * sv);
                    out[((size_t)(b * NH + h) * NS + s) * NHD + hd] = f2bf(o * oscale);
                }
            }
        }
    } else {
        // V^T: out[((b*H+h)*HD+hd)*S + s]
#pragma unroll
        for (int nt = 0; nt < 4; nt++) {
            int gn = n0 + wn + nt * 16 + l15;
            int h = gn >> 6, hd = gn & 63;
            float bvv = biasv[gn];
#pragma unroll
            for (int mt = 0; mt < 4; mt++) {
                int gm0 = m0 + wm + mt * 16 + quad * 4;
                int b = gm0 >> 12, s0 = gm0 & 4095;
                ushort4v pk;
#pragma unroll
                for (int r = 0; r < 4; r++)
                    pk[r] = f2bf(acc[mt][nt][r] + bvv);
                *(ushort4v*)(&Vtb[((size_t)(b * NH + h) * NHD + hd) * NS + s0]) = pk;
            }
        }
    }
}

// Output projection: C = A @ W^T + bias, fp32 out (d_out dtype).
// Swapped operands: D[m=W-row -> quad*4+r][n=seq -> l15].
__global__ __launch_bounds__(256, 2) void gemm_o_kernel(
    const unsigned short* __restrict__ A,
    const unsigned short* __restrict__ Wb,
    const float* __restrict__ bias,
    float* __restrict__ out)
{
    __shared__ unsigned short As[128 * 32];
    __shared__ unsigned short Bs[128 * 32];
    const int t = threadIdx.x;
    const int wave = t >> 6, lane = t & 63;
    const int quad = lane >> 4, l15 = lane & 15;
    const int wm = (wave & 1) * 64, wn = (wave >> 1) * 64;
    const int m0 = blockIdx.y * 128, n0 = blockIdx.x * 128;

    f32x4 acc[4][4];
#pragma unroll
    for (int i = 0; i < 4; i++)
#pragma unroll
        for (int j = 0; j < 4; j++)
            acc[i][j] = f32x4{0.f, 0.f, 0.f, 0.f};

    for (int k0 = 0; k0 < ND; k0 += 32) {
#pragma unroll
        for (int p = 0; p < 2; p++) {
            int idx = p * 256 + t;
            int r = idx >> 2, c = (idx & 3) * 8;
            unsigned short* ldsA = &As[(size_t)(p * 256 + wave * 64) * 8];
            unsigned short* ldsB = &Bs[(size_t)(p * 256 + wave * 64) * 8];
            gload_lds16(&A[(size_t)(m0 + r) * ND + k0 + c], ldsA);
            gload_lds16(&Wb[(size_t)(n0 + r) * ND + k0 + c], ldsB);
        }
        __syncthreads();

        short8 af[4], bfr[4];
#pragma unroll
        for (int mt = 0; mt < 4; mt++)
            af[mt] = *(const short8*)(&As[(wm + mt * 16 + l15) * 32 + quad * 8]);
#pragma unroll
        for (int nt = 0; nt < 4; nt++)
            bfr[nt] = *(const short8*)(&Bs[(wn + nt * 16 + l15) * 32 + quad * 8]);
#pragma unroll
        for (int mt = 0; mt < 4; mt++)
#pragma unroll
            for (int nt = 0; nt < 4; nt++)
                acc[mt][nt] = __builtin_amdgcn_mfma_f32_16x16x32_bf16(bfr[nt], af[mt], acc[mt][nt], 0, 0, 0);
        __syncthreads();
    }

#pragma unroll
    for (int mt = 0; mt < 4; mt++) {
        int gm = m0 + wm + mt * 16 + l15;  // seq row
#pragma unroll
        for (int nt = 0; nt < 4; nt++) {
            int gn0 = n0 + wn + nt * 16 + quad * 4;  // feature
            float4v fv;
#pragma unroll
            for (int r = 0; r < 4; r++)
                fv[r] = acc[mt][nt][r] + bias[gn0 + r];
            *(float4v*)(&out[(size_t)gm * ND + gn0]) = fv;
        }
    }
}

// Flash attention, 32x32-MFMA in-register-P structure (m214-v22 style).
// Qr: [BH][S][64] bf16, RoPE'd AND pre-scaled by 0.125*log2e. Kr: same, unscaled.
// Vt: [BH][64][S] bf16. Yatt: [B*S][1024] bf16.
// Block: 128 q-rows of one (b,h); wave owns 32 q-rows. Per 128-key tile:
//   S^T = K.Q^T via mfma_32x32x16 (A=K rows, B=Q rows). D: col(lane&31)=q,
//   row=(reg&3)+8*(reg>>2)+4*(lane>>5)=key. Each lane: ONE q, 64 of 128 keys;
//   partner lane^32 has the rest -> softmax = in-lane tree + ONE xor32 shfl.
//   P -> bf16 via cvt_pk, then ONE v_permlane32_swap_b32 per register pair
//   assembles PV B-frags in-register. NO P LDS round-trip. LDS 35840 B.
__global__ __launch_bounds__(256, 2) void flash_kernel(
    const unsigned short* __restrict__ Qr,
    const unsigned short* __restrict__ Kr,
    const unsigned short* __restrict__ Vt,
    unsigned short* __restrict__ Yatt)
{
    __shared__ unsigned short Ks[128 * 72];    // pad 64->72 (16B-aligned rows)
    __shared__ unsigned short Vs[64 * 136];    // pad 128->136
    const int t = threadIdx.x;
    const int wave = t >> 6, lane = t & 63;
    const int l31 = lane & 31, h = lane >> 5;
    const int bh = blockIdx.y;
    const int qb = blockIdx.x * 128;
    const int wq = wave * 32;
    const size_t base = (size_t)bh * NS * NHD;

    // Q B-frags: row q = qb+wq+l31, k(d) = ks*16 + h*8 + e
    short8 qf[4];
#pragma unroll
    for (int ks = 0; ks < 4; ks++)
        qf[ks] = *(const short8*)(&Qr[base + (size_t)(qb + wq + l31) * NHD + ks * 16 + h * 8]);

    f32x16 zacc;
#pragma unroll
    for (int r = 0; r < 16; r++)
        zacc[r] = 0.f;

    f32x16 accO[2];
    accO[0] = zacc; accO[1] = zacc;
    float mrow = -1e30f, lrow = 0.f;

    for (int j0 = 0; j0 < NS; j0 += 128) {
        // stage K/V tile
#pragma unroll
        for (int p = 0; p < 4; p++) {
            int idx = p * 256 + t;
            { int r = idx >> 3, c = (idx & 7) * 8;
              *(short8*)(&Ks[r * 72 + c]) = *(const short8*)(&Kr[base + (size_t)(j0 + r) * NHD + c]); }
            { int r = idx >> 4, c = (idx & 15) * 8;
              *(short8*)(&Vs[r * 136 + c]) = *(const short8*)(&Vt[(size_t)(bh * NHD + r) * NS + j0 + c]); }
        }
        __syncthreads();

        // S^T = K . Q^T (exp2 domain; Q pre-scaled)
        f32x16 sa[4];
        __builtin_amdgcn_s_setprio(1);
#pragma unroll
        for (int kt = 0; kt < 4; kt++) {
            short8 ak0 = *(const short8*)(&Ks[(kt * 32 + l31) * 72 + h * 8]);
            f32x16 s = __builtin_amdgcn_mfma_f32_32x32x16_bf16(ak0, qf[0], zacc, 0, 0, 0);
#pragma unroll
            for (int ks = 1; ks < 4; ks++) {
                short8 ak = *(const short8*)(&Ks[(kt * 32 + l31) * 72 + ks * 16 + h * 8]);
                s = __builtin_amdgcn_mfma_f32_32x32x16_bf16(ak, qf[ks], s, 0, 0, 0);
            }
            sa[kt] = s;
        }
        __builtin_amdgcn_s_setprio(0);

        // --- softmax: each lane owns one q (l31), 64 of 128 keys ---
        float mx = -1e30f;
#pragma unroll
        for (int kt = 0; kt < 4; kt++) {
            float m0v = fmaxf(fmaxf(sa[kt][0], sa[kt][1]), fmaxf(sa[kt][2], sa[kt][3]));
            float m1v = fmaxf(fmaxf(sa[kt][4], sa[kt][5]), fmaxf(sa[kt][6], sa[kt][7]));
            float m2v = fmaxf(fmaxf(sa[kt][8], sa[kt][9]), fmaxf(sa[kt][10], sa[kt][11]));
            float m3v = fmaxf(fmaxf(sa[kt][12], sa[kt][13]), fmaxf(sa[kt][14], sa[kt][15]));
            mx = fmaxf(mx, fmaxf(fmaxf(m0v, m1v), fmaxf(m2v, m3v)));
        }
        mx = fmaxf(mx, __shfl_xor(mx, 32, 64));
        // T13 defer-max: rescale only when tile max exceeds running max by >8
        if (!__all(mx <= mrow + 8.0f)) {
            float mnew = fmaxf(mrow, mx);
            float alpha = exp2f(mrow - mnew);
            lrow *= alpha;
#pragma unroll
            for (int dt = 0; dt < 2; dt++)
#pragma unroll
                for (int r = 0; r < 16; r++)
                    accO[dt][r] *= alpha;
            mrow = mnew;
        }
        float ls0 = 0.f, ls1 = 0.f, ls2 = 0.f, ls3 = 0.f;
        unsigned pk[4][4][2];  // [key-tile][quartet g][pair j]
#pragma unroll
        for (int kt = 0; kt < 4; kt++)
#pragma unroll
            for (int g = 0; g < 4; g++) {
                float p0 = exp2f(sa[kt][4 * g + 0] - mrow);
                float p1 = exp2f(sa[kt][4 * g + 1] - mrow);
                float p2 = exp2f(sa[kt][4 * g + 2] - mrow);
                float p3 = exp2f(sa[kt][4 * g + 3] - mrow);
                ls0 += p0; ls1 += p1; ls2 += p2; ls3 += p3;
                pk[kt][g][0] = cvt_pk_bf16(p0, p1);
                pk[kt][g][1] = cvt_pk_bf16(p2, p3);
            }
        float lsum = (ls0 + ls1) + (ls2 + ls3);
        lsum += __shfl_xor(lsum, 32, 64);
        lrow += lsum;

        // in-register P redistribution: swap vdst_hi <-> vsrc_lo.
#pragma unroll
        for (int t2 = 0; t2 < 4; t2++)
#pragma unroll
            for (int u = 0; u < 2; u++)
#pragma unroll
                for (int j = 0; j < 2; j++)
                    asm volatile("v_permlane32_swap_b32 %0, %1"
                                 : "+v"(pk[t2][2 * u][j]), "+v"(pk[t2][2 * u + 1][j]));

        // PV: O^T[d][q] += V^T . P^T, B-frag assembled from swapped pk
        __builtin_amdgcn_s_setprio(1);
#pragma unroll
        for (int ks2 = 0; ks2 < 8; ks2++) {
            const int t2 = ks2 >> 1, u = ks2 & 1;
            uint32x4 bw;
            bw.x = pk[t2][2 * u][0];     bw.y = pk[t2][2 * u][1];
            bw.z = pk[t2][2 * u + 1][0]; bw.w = pk[t2][2 * u + 1][1];
            short8 bp = __builtin_bit_cast(short8, bw);
#pragma unroll
            for (int dt = 0; dt < 2; dt++) {
                short8 av = *(const short8*)(&Vs[(dt * 32 + l31) * 136 + ks2 * 16 + h * 8]);
                accO[dt] = __builtin_amdgcn_mfma_f32_32x32x16_bf16(av, bp, accO[dt], 0, 0, 0);
            }
        }
        __builtin_amdgcn_s_setprio(0);
        __syncthreads();
    }

    // epilogue: lane owns q = l31; accO row = 8g + 4h + (reg&3) within dt*32
    int b = bh >> 4, hh = bh & 15;
    float rl = 1.f / lrow;
    int s = qb + wq + l31;
#pragma unroll
    for (int dt = 0; dt < 2; dt++)
#pragma unroll
        for (int g = 0; g < 4; g++) {
            uint32x2 w;
            w.x = cvt_pk_bf16(accO[dt][4 * g + 0] * rl, accO[dt][4 * g + 1] * rl);
            w.y = cvt_pk_bf16(accO[dt][4 * g + 2] * rl, accO[dt][4 * g + 3] * rl);
            int d0 = dt * 32 + 8 * g + 4 * h;
            *(uint32x2*)(&Yatt[((size_t)(b * NS + s)) * ND + hh * NHD + d0]) = w;
        }
}

extern "C" void kernel_launch(void* const* d_in, const int* in_sizes, int n_in,
                              void* d_out, int out_size, void* d_ws, size_t ws_size,
                              hipStream_t stream) {
    // dict order (contractual): consulta, chave, valor, Wq, bq, Wk, bk, Wv, bv, Wo, bo
    const float* consulta = (const float*)d_in[0];
    const float* chave    = (const float*)d_in[1];
    const float* valor    = (const float*)d_in[2];
    const float* Wq = (const float*)d_in[3];
    const float* bq = (const float*)d_in[4];
    const float* Wk = (const float*)d_in[5];
    const float* bk = (const float*)d_in[6];
    const float* Wv = (const float*)d_in[7];
    const float* bv = (const float*)d_in[8];
    const float* Wo = (const float*)d_in[9];
    const float* bo = (const float*)d_in[10];

    const size_t NX = (size_t)8192 * 1024;       // activation elems
    const size_t NW = (size_t)ND * ND;           // one weight's elems

    const int ACT8 = (int)(NX / 8);   // 1048576 vec8 chunks
    const int W8 = (int)(NW / 8);     // 131072

    // Layout. Merged mode needs 3 activations live at once (~125 MB);
    // fallback (proven <=97 MB footprint) reuses one activation slot.
    float* cosT = (float*)d_ws;
    float* sinT = cosT + (size_t)NS * 32;
    unsigned short* Qrb = (unsigned short*)(sinT + (size_t)NS * 32);
    unsigned short* Krb = Qrb + NX;
    unsigned short* Vtb = Krb + NX;
    unsigned short* Yat = Vtb + NX;
    unsigned short* A0  = Yat + NX;

    const size_t need_merged =
        (size_t)NS * 32 * 2 * sizeof(float) + (4 + 3) * NX * 2 + 3 * NW * 2;
    const bool merged = ws_size >= need_merged;

    rope_table_kernel<<<NS * 32 / 256, 256, 0, stream>>>(cosT, sinT);

    if (merged) {
        unsigned short* A1 = A0 + NX;
        unsigned short* A2 = A1 + NX;
        unsigned short* W3 = A2 + NX;   // stacked [3072][1024]

        cast_bf16_kernel<<<ACT8 / 256, 256, 0, stream>>>(consulta, A0, ACT8);
        cast_bf16_kernel<<<ACT8 / 256, 256, 0, stream>>>(chave,    A1, ACT8);
        cast_bf16_kernel<<<ACT8 / 256, 256, 0, stream>>>(valor,    A2, ACT8);
        cast_bf16_kernel<<<W8 / 256, 256, 0, stream>>>(Wq, W3,          W8);
        cast_bf16_kernel<<<W8 / 256, 256, 0, stream>>>(Wk, W3 + NW,     W8);
        cast_bf16_kernel<<<W8 / 256, 256, 0, stream>>>(Wv, W3 + 2 * NW, W8);

        gemm_qkv_kernel<<<dim3(24, 64), 256, 0, stream>>>(
            A0, A1, A2, W3, bq, bk, bv, Qrb, Krb, Vtb, cosT, sinT, 0);

        flash_kernel<<<dim3(32, 32), 256, 0, stream>>>(Qrb, Krb, Vtb, Yat);

        cast_bf16_kernel<<<W8 / 256, 256, 0, stream>>>(Wo, W3, W8);
        gemm_o_kernel<<<dim3(8, 64), 256, 0, stream>>>(Yat, W3, bo, (float*)d_out);
    } else {
        unsigned short* W3 = A0 + NX;   // single weight slot

        const float* acts[3]  = {consulta, chave, valor};
        const float* ws[3]    = {Wq, Wk, Wv};
        for (int i = 0; i < 3; i++) {
            cast_bf16_kernel<<<ACT8 / 256, 256, 0, stream>>>(acts[i], A0, ACT8);
            cast_bf16_kernel<<<W8 / 256, 256, 0, stream>>>(ws[i], W3, W8);
            gemm_qkv_kernel<<<dim3(8, 64), 256, 0, stream>>>(
                A0, A0, A0, W3, bq, bk, bv, Qrb, Krb, Vtb, cosT, sinT, i);
        }

        flash_kernel<<<dim3(32, 32), 256, 0, stream>>>(Qrb, Krb, Vtb, Yat);

        cast_bf16_kernel<<<W8 / 256, 256, 0, stream>>>(Wo, W3, W8);
        gemm_o_kernel<<<dim3(8, 64), 256, 0, stream>>>(Yat, W3, bo, (float*)d_out);
    }
}

// Round 9
// 506.732 us; speedup vs baseline: 1.0501x; 1.0349x over previous
//
#include <hip/hip_runtime.h>
#include <hip/hip_bf16.h>

typedef __attribute__((ext_vector_type(8))) short short8;
typedef __attribute__((ext_vector_type(4))) float f32x4;
typedef __attribute__((ext_vector_type(16))) float f32x16;
typedef __attribute__((ext_vector_type(4))) unsigned short ushort4v;
typedef __attribute__((ext_vector_type(4))) float float4v;
typedef __attribute__((ext_vector_type(2))) unsigned int uint32x2;
typedef __attribute__((ext_vector_type(4))) unsigned int uint32x4;

#define NB 2
#define NS 4096
#define ND 1024
#define NH 16
#define NHD 64

// 0.125 * log2(e): folds the 1/sqrt(64) score scale AND the exp->exp2
// conversion into the Q projection (exact up to one fp32 rounding).
#define QSCALE 0.18033688011112042f

__device__ __forceinline__ unsigned short f2bf(float x) {
    union { float f; unsigned u; } v; v.f = x;
    unsigned r = v.u + 0x7FFFu + ((v.u >> 16) & 1u);
    return (unsigned short)(r >> 16);
}

// pack 2 f32 -> u32 of 2 bf16 (RNE), dst[15:0]=lo
__device__ __forceinline__ unsigned cvt_pk_bf16(float lo, float hi) {
    unsigned r;
    asm("v_cvt_pk_bf16_f32 %0, %1, %2" : "=v"(r) : "v"(lo), "v"(hi));
    return r;
}

// async global->LDS, 16B per lane. LDS dest = wave-uniform base + lane*16.
__device__ __forceinline__ void gload_lds16(const unsigned short* g, unsigned short* l) {
    __builtin_amdgcn_global_load_lds(
        (const __attribute__((address_space(1))) void*)g,
        (__attribute__((address_space(3))) void*)l,
        16, 0, 0);
}

__global__ void rope_table_kernel(float* __restrict__ cosT, float* __restrict__ sinT) {
    int i = blockIdx.x * blockDim.x + threadIdx.x;  // [0, NS*32)
    int p = i & 31, s = i >> 5;
    float theta = exp2f(-(float)(2 * p) * (13.287712379549449f / 64.0f));  // 10000^(-2p/64)
    float ang = (float)s * theta;
    float sv, cv;
    sincosf(ang, &sv, &cv);
    cosT[i] = cv; sinT[i] = sv;
}

// fp32 -> bf16 elementwise cast, 8 elems/thread (32B read, 16B write).
__global__ void cast_bf16_kernel(const float* __restrict__ in, unsigned short* __restrict__ out, int n8) {
    int i = blockIdx.x * blockDim.x + threadIdx.x;
    if (i >= n8) return;
    float4v a0 = *(const float4v*)(&in[(size_t)i * 8]);
    float4v a1 = *(const float4v*)(&in[(size_t)i * 8 + 4]);
    short8 s8;
    s8[0] = (short)f2bf(a0.x); s8[1] = (short)f2bf(a0.y);
    s8[2] = (short)f2bf(a0.z); s8[3] = (short)f2bf(a0.w);
    s8[4] = (short)f2bf(a1.x); s8[5] = (short)f2bf(a1.y);
    s8[6] = (short)f2bf(a1.z); s8[7] = (short)f2bf(a1.w);
    *(short8*)(&out[(size_t)i * 8]) = s8;
}

// Fused QKV projection GEMM, round-9: double-buffered LDS prefetch + XCD-
// chunked blockIdx swizzle. W3: stacked [3072][1024] bf16 (Wq;Wk;Wv) in
// merged mode, single weight in fallback. which = (n0g>>10)+which_base:
// 0 -> Q (RoPE, QSCALE), 1 -> K (RoPE), 2 -> V^T.
// Per iter: issue NEXT tile's global_load_lds, ds_read+MFMA on current,
// ONE barrier (vmcnt drain now waits only residual latency).
__global__ __launch_bounds__(256, 2) void gemm_qkv_kernel(
    const unsigned short* __restrict__ A0,
    const unsigned short* __restrict__ A1,
    const unsigned short* __restrict__ A2,
    const unsigned short* __restrict__ W3,
    const float* __restrict__ biasq,
    const float* __restrict__ biask,
    const float* __restrict__ biasv,
    unsigned short* __restrict__ Qrb,
    unsigned short* __restrict__ Krb,
    unsigned short* __restrict__ Vtb,
    const float* __restrict__ cosT,
    const float* __restrict__ sinT,
    int which_base)
{
    __shared__ unsigned short As[2][128 * 32];  // dbuf, linear (gload_lds)
    __shared__ unsigned short Bs[2][128 * 32];
    const int t = threadIdx.x;
    const int wave = t >> 6, lane = t & 63;
    const int quad = lane >> 4, l15 = lane & 15;
    const int wm = (wave & 1) * 64, wn = (wave >> 1) * 64;

    // XCD-chunked bijective swizzle (all grids have nwg % 8 == 0):
    // each XCD gets a contiguous chunk -> blocks sharing an A-panel (same by)
    // land on ONE XCD's L2 instead of being round-robined across all 8.
    const int gx = gridDim.x;
    const int nwg = gx * gridDim.y;
    const int flat = blockIdx.y * gx + blockIdx.x;
    const int nf = (flat & 7) * (nwg >> 3) + (flat >> 3);
    const int bx = nf % gx, by = nf / gx;

    const int m0 = by * 128;
    const int n0g = bx * 128;                      // row into stacked W3
    const int which = (n0g >> 10) + which_base;    // 0=Q 1=K 2=V
    const int n0 = n0g & 1023;                     // feature within head-dim space
    const unsigned short* A = (which == 0) ? A0 : (which == 1) ? A1 : A2;

    f32x4 acc[4][4];
#pragma unroll
    for (int i = 0; i < 4; i++)
#pragma unroll
        for (int j = 0; j < 4; j++)
            acc[i][j] = f32x4{0.f, 0.f, 0.f, 0.f};

    // prologue: stage k-tile 0 into buffer 0
#pragma unroll
    for (int p = 0; p < 2; p++) {
        int idx = p * 256 + t;
        int r = idx >> 2, c = (idx & 3) * 8;
        gload_lds16(&A[(size_t)(m0 + r) * ND + c], &As[0][(p * 256 + wave * 64) * 8]);
        gload_lds16(&W3[(size_t)(n0g + r) * ND + c], &Bs[0][(p * 256 + wave * 64) * 8]);
    }
    __syncthreads();

    int cur = 0;
    for (int k0 = 0; k0 < ND; k0 += 32) {
        // prefetch next k-tile into the other buffer (async, in flight
        // across the ds_read+MFMA below)
        if (k0 + 32 < ND) {
            int nb = cur ^ 1, k1 = k0 + 32;
#pragma unroll
            for (int p = 0; p < 2; p++) {
                int idx = p * 256 + t;
                int r = idx >> 2, c = (idx & 3) * 8;
                gload_lds16(&A[(size_t)(m0 + r) * ND + k1 + c], &As[nb][(p * 256 + wave * 64) * 8]);
                gload_lds16(&W3[(size_t)(n0g + r) * ND + k1 + c], &Bs[nb][(p * 256 + wave * 64) * 8]);
            }
        }

        short8 af[4], bfr[4];
#pragma unroll
        for (int mt = 0; mt < 4; mt++)
            af[mt] = *(const short8*)(&As[cur][(wm + mt * 16 + l15) * 32 + quad * 8]);
#pragma unroll
        for (int nt = 0; nt < 4; nt++)
            bfr[nt] = *(const short8*)(&Bs[cur][(wn + nt * 16 + l15) * 32 + quad * 8]);
#pragma unroll
        for (int mt = 0; mt < 4; mt++)
#pragma unroll
            for (int nt = 0; nt < 4; nt++)
                acc[mt][nt] = __builtin_amdgcn_mfma_f32_16x16x32_bf16(af[mt], bfr[nt], acc[mt][nt], 0, 0, 0);

        __syncthreads();  // drains prefetch (residual latency only) + WAR on cur
        cur ^= 1;
    }

    if (which < 2) {
        // RoPE epilogue. D[m=seq -> quad*4+r][n=feature -> l15]
        unsigned short* out = (which == 0) ? Qrb : Krb;
        const float* bias = (which == 0) ? biasq : biask;
        const float oscale = (which == 0) ? QSCALE : 1.0f;
#pragma unroll
        for (int nt = 0; nt < 4; nt++) {
            int gn = n0 + wn + nt * 16 + l15;
            int h = gn >> 6, hd = gn & 63, pr = hd >> 1, im = gn & 1;
            float bvv = bias[gn];
#pragma unroll
            for (int mt = 0; mt < 4; mt++) {
                int gm0 = m0 + wm + mt * 16 + quad * 4;
#pragma unroll
                for (int r = 0; r < 4; r++) {
                    int gm = gm0 + r;
                    int b = gm >> 12, s = gm & 4095;
                    float v = acc[mt][nt][r] + bvv;
                    float pv = __shfl_xor(v, 1, 64);  // partner feature gn^1, same seq
                    float cv = cosT[s * 32 + pr], sv = sinT[s * 32 + pr];
                    float o = im ? (pv * sv + v * cv) : (v * cv - pv * sv);
                    out[((size_t)(b * NH + h) * NS + s) * NHD + hd] = f2bf(o * oscale);
                }
            }
        }
    } else {
        // V^T: out[((b*H+h)*HD+hd)*S + s]
#pragma unroll
        for (int nt = 0; nt < 4; nt++) {
            int gn = n0 + wn + nt * 16 + l15;
            int h = gn >> 6, hd = gn & 63;
            float bvv = biasv[gn];
#pragma unroll
            for (int mt = 0; mt < 4; mt++) {
                int gm0 = m0 + wm + mt * 16 + quad * 4;
                int b = gm0 >> 12, s0 = gm0 & 4095;
                ushort4v pk;
#pragma unroll
                for (int r = 0; r < 4; r++)
                    pk[r] = f2bf(acc[mt][nt][r] + bvv);
                *(ushort4v*)(&Vtb[((size_t)(b * NH + h) * NHD + hd) * NS + s0]) = pk;
            }
        }
    }
}

// Output projection: C = A @ W^T + bias, fp32 out (d_out dtype).
// Same round-9 structure: dbuf prefetch + XCD swizzle.
// Swapped operands: D[m=W-row -> quad*4+r][n=seq -> l15].
__global__ __launch_bounds__(256, 2) void gemm_o_kernel(
    const unsigned short* __restrict__ A,
    const unsigned short* __restrict__ Wb,
    const float* __restrict__ bias,
    float* __restrict__ out)
{
    __shared__ unsigned short As[2][128 * 32];
    __shared__ unsigned short Bs[2][128 * 32];
    const int t = threadIdx.x;
    const int wave = t >> 6, lane = t & 63;
    const int quad = lane >> 4, l15 = lane & 15;
    const int wm = (wave & 1) * 64, wn = (wave >> 1) * 64;

    const int gx = gridDim.x;
    const int nwg = gx * gridDim.y;
    const int flat = blockIdx.y * gx + blockIdx.x;
    const int nf = (flat & 7) * (nwg >> 3) + (flat >> 3);
    const int bx = nf % gx, by = nf / gx;
    const int m0 = by * 128, n0 = bx * 128;

    f32x4 acc[4][4];
#pragma unroll
    for (int i = 0; i < 4; i++)
#pragma unroll
        for (int j = 0; j < 4; j++)
            acc[i][j] = f32x4{0.f, 0.f, 0.f, 0.f};

#pragma unroll
    for (int p = 0; p < 2; p++) {
        int idx = p * 256 + t;
        int r = idx >> 2, c = (idx & 3) * 8;
        gload_lds16(&A[(size_t)(m0 + r) * ND + c], &As[0][(p * 256 + wave * 64) * 8]);
        gload_lds16(&Wb[(size_t)(n0 + r) * ND + c], &Bs[0][(p * 256 + wave * 64) * 8]);
    }
    __syncthreads();

    int cur = 0;
    for (int k0 = 0; k0 < ND; k0 += 32) {
        if (k0 + 32 < ND) {
            int nb = cur ^ 1, k1 = k0 + 32;
#pragma unroll
            for (int p = 0; p < 2; p++) {
                int idx = p * 256 + t;
                int r = idx >> 2, c = (idx & 3) * 8;
                gload_lds16(&A[(size_t)(m0 + r) * ND + k1 + c], &As[nb][(p * 256 + wave * 64) * 8]);
                gload_lds16(&Wb[(size_t)(n0 + r) * ND + k1 + c], &Bs[nb][(p * 256 + wave * 64) * 8]);
            }
        }

        short8 af[4], bfr[4];
#pragma unroll
        for (int mt = 0; mt < 4; mt++)
            af[mt] = *(const short8*)(&As[cur][(wm + mt * 16 + l15) * 32 + quad * 8]);
#pragma unroll
        for (int nt = 0; nt < 4; nt++)
            bfr[nt] = *(const short8*)(&Bs[cur][(wn + nt * 16 + l15) * 32 + quad * 8]);
#pragma unroll
        for (int mt = 0; mt < 4; mt++)
#pragma unroll
            for (int nt = 0; nt < 4; nt++)
                acc[mt][nt] = __builtin_amdgcn_mfma_f32_16x16x32_bf16(bfr[nt], af[mt], acc[mt][nt], 0, 0, 0);

        __syncthreads();
        cur ^= 1;
    }

#pragma unroll
    for (int mt = 0; mt < 4; mt++) {
        int gm = m0 + wm + mt * 16 + l15;  // seq row
#pragma unroll
        for (int nt = 0; nt < 4; nt++) {
            int gn0 = n0 + wn + nt * 16 + quad * 4;  // feature
            float4v fv;
#pragma unroll
            for (int r = 0; r < 4; r++)
                fv[r] = acc[mt][nt][r] + bias[gn0 + r];
            *(float4v*)(&out[(size_t)gm * ND + gn0]) = fv;
        }
    }
}

// Flash attention, 32x32-MFMA in-register-P structure (m214-v22 style).
// Qr: [BH][S][64] bf16, RoPE'd AND pre-scaled by 0.125*log2e. Kr: same, unscaled.
// Vt: [BH][64][S] bf16. Yatt: [B*S][1024] bf16.
// Block: 128 q-rows of one (b,h); wave owns 32 q-rows. Per 128-key tile:
//   S^T = K.Q^T via mfma_32x32x16 (A=K rows, B=Q rows). D: col(lane&31)=q,
//   row=(reg&3)+8*(reg>>2)+4*(lane>>5)=key. Each lane: ONE q, 64 of 128 keys;
//   partner lane^32 has the rest -> softmax = in-lane tree + ONE xor32 shfl.
//   P -> bf16 via cvt_pk, then ONE v_permlane32_swap_b32 per register pair
//   assembles PV B-frags in-register. NO P LDS round-trip. LDS 35840 B.
__global__ __launch_bounds__(256, 2) void flash_kernel(
    const unsigned short* __restrict__ Qr,
    const unsigned short* __restrict__ Kr,
    const unsigned short* __restrict__ Vt,
    unsigned short* __restrict__ Yatt)
{
    __shared__ unsigned short Ks[128 * 72];    // pad 64->72 (16B-aligned rows)
    __shared__ unsigned short Vs[64 * 136];    // pad 128->136
    const int t = threadIdx.x;
    const int wave = t >> 6, lane = t & 63;
    const int l31 = lane & 31, h = lane >> 5;
    const int bh = blockIdx.y;
    const int qb = blockIdx.x * 128;
    const int wq = wave * 32;
    const size_t base = (size_t)bh * NS * NHD;

    // Q B-frags: row q = qb+wq+l31, k(d) = ks*16 + h*8 + e
    short8 qf[4];
#pragma unroll
    for (int ks = 0; ks < 4; ks++)
        qf[ks] = *(const short8*)(&Qr[base + (size_t)(qb + wq + l31) * NHD + ks * 16 + h * 8]);

    f32x16 zacc;
#pragma unroll
    for (int r = 0; r < 16; r++)
        zacc[r] = 0.f;

    f32x16 accO[2];
    accO[0] = zacc; accO[1] = zacc;
    float mrow = -1e30f, lrow = 0.f;

    for (int j0 = 0; j0 < NS; j0 += 128) {
        // stage K/V tile
#pragma unroll
        for (int p = 0; p < 4; p++) {
            int idx = p * 256 + t;
            { int r = idx >> 3, c = (idx & 7) * 8;
              *(short8*)(&Ks[r * 72 + c]) = *(const short8*)(&Kr[base + (size_t)(j0 + r) * NHD + c]); }
            { int r = idx >> 4, c = (idx & 15) * 8;
              *(short8*)(&Vs[r * 136 + c]) = *(const short8*)(&Vt[(size_t)(bh * NHD + r) * NS + j0 + c]); }
        }
        __syncthreads();

        // S^T = K . Q^T (exp2 domain; Q pre-scaled)
        f32x16 sa[4];
        __builtin_amdgcn_s_setprio(1);
#pragma unroll
        for (int kt = 0; kt < 4; kt++) {
            short8 ak0 = *(const short8*)(&Ks[(kt * 32 + l31) * 72 + h * 8]);
            f32x16 s = __builtin_amdgcn_mfma_f32_32x32x16_bf16(ak0, qf[0], zacc, 0, 0, 0);
#pragma unroll
            for (int ks = 1; ks < 4; ks++) {
                short8 ak = *(const short8*)(&Ks[(kt * 32 + l31) * 72 + ks * 16 + h * 8]);
                s = __builtin_amdgcn_mfma_f32_32x32x16_bf16(ak, qf[ks], s, 0, 0, 0);
            }
            sa[kt] = s;
        }
        __builtin_amdgcn_s_setprio(0);

        // --- softmax: each lane owns one q (l31), 64 of 128 keys ---
        float mx = -1e30f;
#pragma unroll
        for (int kt = 0; kt < 4; kt++) {
            float m0v = fmaxf(fmaxf(sa[kt][0], sa[kt][1]), fmaxf(sa[kt][2], sa[kt][3]));
            float m1v = fmaxf(fmaxf(sa[kt][4], sa[kt][5]), fmaxf(sa[kt][6], sa[kt][7]));
            float m2v = fmaxf(fmaxf(sa[kt][8], sa[kt][9]), fmaxf(sa[kt][10], sa[kt][11]));
            float m3v = fmaxf(fmaxf(sa[kt][12], sa[kt][13]), fmaxf(sa[kt][14], sa[kt][15]));
            mx = fmaxf(mx, fmaxf(fmaxf(m0v, m1v), fmaxf(m2v, m3v)));
        }
        mx = fmaxf(mx, __shfl_xor(mx, 32, 64));
        // T13 defer-max: rescale only when tile max exceeds running max by >8
        if (!__all(mx <= mrow + 8.0f)) {
            float mnew = fmaxf(mrow, mx);
            float alpha = exp2f(mrow - mnew);
            lrow *= alpha;
#pragma unroll
            for (int dt = 0; dt < 2; dt++)
#pragma unroll
                for (int r = 0; r < 16; r++)
                    accO[dt][r] *= alpha;
            mrow = mnew;
        }
        float ls0 = 0.f, ls1 = 0.f, ls2 = 0.f, ls3 = 0.f;
        unsigned pk[4][4][2];  // [key-tile][quartet g][pair j]
#pragma unroll
        for (int kt = 0; kt < 4; kt++)
#pragma unroll
            for (int g = 0; g < 4; g++) {
                float p0 = exp2f(sa[kt][4 * g + 0] - mrow);
                float p1 = exp2f(sa[kt][4 * g + 1] - mrow);
                float p2 = exp2f(sa[kt][4 * g + 2] - mrow);
                float p3 = exp2f(sa[kt][4 * g + 3] - mrow);
                ls0 += p0; ls1 += p1; ls2 += p2; ls3 += p3;
                pk[kt][g][0] = cvt_pk_bf16(p0, p1);
                pk[kt][g][1] = cvt_pk_bf16(p2, p3);
            }
        float lsum = (ls0 + ls1) + (ls2 + ls3);
        lsum += __shfl_xor(lsum, 32, 64);
        lrow += lsum;

        // in-register P redistribution: swap vdst_hi <-> vsrc_lo.
#pragma unroll
        for (int t2 = 0; t2 < 4; t2++)
#pragma unroll
            for (int u = 0; u < 2; u++)
#pragma unroll
                for (int j = 0; j < 2; j++)
                    asm volatile("v_permlane32_swap_b32 %0, %1"
                                 : "+v"(pk[t2][2 * u][j]), "+v"(pk[t2][2 * u + 1][j]));

        // PV: O^T[d][q] += V^T . P^T, B-frag assembled from swapped pk
        __builtin_amdgcn_s_setprio(1);
#pragma unroll
        for (int ks2 = 0; ks2 < 8; ks2++) {
            const int t2 = ks2 >> 1, u = ks2 & 1;
            uint32x4 bw;
            bw.x = pk[t2][2 * u][0];     bw.y = pk[t2][2 * u][1];
            bw.z = pk[t2][2 * u + 1][0]; bw.w = pk[t2][2 * u + 1][1];
            short8 bp = __builtin_bit_cast(short8, bw);
#pragma unroll
            for (int dt = 0; dt < 2; dt++) {
                short8 av = *(const short8*)(&Vs[(dt * 32 + l31) * 136 + ks2 * 16 + h * 8]);
                accO[dt] = __builtin_amdgcn_mfma_f32_32x32x16_bf16(av, bp, accO[dt], 0, 0, 0);
            }
        }
        __builtin_amdgcn_s_setprio(0);
        __syncthreads();
    }

    // epilogue: lane owns q = l31; accO row = 8g + 4h + (reg&3) within dt*32
    int b = bh >> 4, hh = bh & 15;
    float rl = 1.f / lrow;
    int s = qb + wq + l31;
#pragma unroll
    for (int dt = 0; dt < 2; dt++)
#pragma unroll
        for (int g = 0; g < 4; g++) {
            uint32x2 w;
            w.x = cvt_pk_bf16(accO[dt][4 * g + 0] * rl, accO[dt][4 * g + 1] * rl);
            w.y = cvt_pk_bf16(accO[dt][4 * g + 2] * rl, accO[dt][4 * g + 3] * rl);
            int d0 = dt * 32 + 8 * g + 4 * h;
            *(uint32x2*)(&Yatt[((size_t)(b * NS + s)) * ND + hh * NHD + d0]) = w;
        }
}

extern "C" void kernel_launch(void* const* d_in, const int* in_sizes, int n_in,
                              void* d_out, int out_size, void* d_ws, size_t ws_size,
                              hipStream_t stream) {
    // dict order (contractual): consulta, chave, valor, Wq, bq, Wk, bk, Wv, bv, Wo, bo
    const float* consulta = (const float*)d_in[0];
    const float* chave    = (const float*)d_in[1];
    const float* valor    = (const float*)d_in[2];
    const float* Wq = (const float*)d_in[3];
    const float* bq = (const float*)d_in[4];
    const float* Wk = (const float*)d_in[5];
    const float* bk = (const float*)d_in[6];
    const float* Wv = (const float*)d_in[7];
    const float* bv = (const float*)d_in[8];
    const float* Wo = (const float*)d_in[9];
    const float* bo = (const float*)d_in[10];

    const size_t NX = (size_t)8192 * 1024;       // activation elems
    const size_t NW = (size_t)ND * ND;           // one weight's elems

    const int ACT8 = (int)(NX / 8);   // 1048576 vec8 chunks
    const int W8 = (int)(NW / 8);     // 131072

    // Layout. Merged mode needs 3 activations live at once (~125 MB);
    // fallback (proven <=97 MB footprint) reuses one activation slot.
    float* cosT = (float*)d_ws;
    float* sinT = cosT + (size_t)NS * 32;
    unsigned short* Qrb = (unsigned short*)(sinT + (size_t)NS * 32);
    unsigned short* Krb = Qrb + NX;
    unsigned short* Vtb = Krb + NX;
    unsigned short* Yat = Vtb + NX;
    unsigned short* A0  = Yat + NX;

    const size_t need_merged =
        (size_t)NS * 32 * 2 * sizeof(float) + (4 + 3) * NX * 2 + 3 * NW * 2;
    const bool merged = ws_size >= need_merged;

    rope_table_kernel<<<NS * 32 / 256, 256, 0, stream>>>(cosT, sinT);

    if (merged) {
        unsigned short* A1 = A0 + NX;
        unsigned short* A2 = A1 + NX;
        unsigned short* W3 = A2 + NX;   // stacked [3072][1024]

        cast_bf16_kernel<<<ACT8 / 256, 256, 0, stream>>>(consulta, A0, ACT8);
        cast_bf16_kernel<<<ACT8 / 256, 256, 0, stream>>>(chave,    A1, ACT8);
        cast_bf16_kernel<<<ACT8 / 256, 256, 0, stream>>>(valor,    A2, ACT8);
        cast_bf16_kernel<<<W8 / 256, 256, 0, stream>>>(Wq, W3,          W8);
        cast_bf16_kernel<<<W8 / 256, 256, 0, stream>>>(Wk, W3 + NW,     W8);
        cast_bf16_kernel<<<W8 / 256, 256, 0, stream>>>(Wv, W3 + 2 * NW, W8);

        gemm_qkv_kernel<<<dim3(24, 64), 256, 0, stream>>>(
            A0, A1, A2, W3, bq, bk, bv, Qrb, Krb, Vtb, cosT, sinT, 0);

        flash_kernel<<<dim3(32, 32), 256, 0, stream>>>(Qrb, Krb, Vtb, Yat);

        cast_bf16_kernel<<<W8 / 256, 256, 0, stream>>>(Wo, W3, W8);
        gemm_o_kernel<<<dim3(8, 64), 256, 0, stream>>>(Yat, W3, bo, (float*)d_out);
    } else {
        unsigned short* W3 = A0 + NX;   // single weight slot

        const float* acts[3]  = {consulta, chave, valor};
        const float* ws[3]    = {Wq, Wk, Wv};
        for (int i = 0; i < 3; i++) {
            cast_bf16_kernel<<<ACT8 / 256, 256, 0, stream>>>(acts[i], A0, ACT8);
            cast_bf16_kernel<<<W8 / 256, 256, 0, stream>>>(ws[i], W3, W8);
            gemm_qkv_kernel<<<dim3(8, 64), 256, 0, stream>>>(
                A0, A0, A0, W3, bq, bk, bv, Qrb, Krb, Vtb, cosT, sinT, i);
        }

        flash_kernel<<<dim3(32, 32), 256, 0, stream>>>(Qrb, Krb, Vtb, Yat);

        cast_bf16_kernel<<<W8 / 256, 256, 0, stream>>>(Wo, W3, W8);
        gemm_o_kernel<<<dim3(8, 64), 256, 0, stream>>>(Yat, W3, bo, (float*)d_out);
    }
}